// Round 1
// baseline (992.978 us; speedup 1.0000x reference)
//
#include <hip/hip_runtime.h>
#include <stdint.h>

// LSTMNet: B=2048, T=512, IN=64, H=64, 4H=256, 2 layers, FC to 4 classes.
// Strategy: 256 WGs x 512 threads; each WG owns 8 batches through both layers
// and all 512 timesteps (fully fused; h1 sequence never materialized).
// Weights are held in VGPRs as MFMA B-fragments for the whole kernel.
// Precision: "hi/lo-in-M" bf16x4 — M rows 0-7 = bf16_hi(inp), rows 8-15 =
// bf16_lo(inp); two B passes (W_hi, W_lo); fold C[m]+C[m+8] => fp32-grade.

#define T_SEQ 512
#define NB    8            // batches per workgroup
#define PSTR  132          // A-panel row stride (bf16 elems); 264B => conflict-free ds_read_b64
#define GSTR  257          // gate buffer row stride (f32);    => conflict-free C stores

typedef __attribute__((ext_vector_type(8))) short  short8;   // 8 x bf16 (4 VGPRs)
typedef __attribute__((ext_vector_type(4))) float  float4v;  // MFMA C/D

__device__ __forceinline__ unsigned short f2bf(float f) {
    unsigned int u = __builtin_bit_cast(unsigned int, f);
    return (unsigned short)((u + 0x7FFFu + ((u >> 16) & 1u)) >> 16);  // RNE
}
__device__ __forceinline__ float bf2f(unsigned short h) {
    unsigned int u = ((unsigned int)h) << 16;
    return __builtin_bit_cast(float, u);
}
__device__ __forceinline__ float sigm(float x) {
    return __builtin_amdgcn_rcpf(1.0f + __builtin_amdgcn_exp2f(-1.44269504088896f * x));
}
__device__ __forceinline__ float tanh_f(float x) {
    float a = __builtin_fabsf(x);
    float e = __builtin_amdgcn_exp2f(-2.88539008177793f * a);  // exp(-2a)
    float t = (1.0f - e) * __builtin_amdgcn_rcpf(1.0f + e);
    return __builtin_copysignf(t, x);
}

// One layer's gate matmul: gates[16,256] = Apanel[16,128] @ W[128,256], two
// passes (W_hi then W_lo) accumulated into the same C. C written to gb.
template<int L>
__device__ __forceinline__ void mfma_phase(const unsigned short* panel,
        const short8 (&whi)[2][2][4], const short8 (&wlo)[2][2][4],
        float* gb, int wave, int lane)
{
    const int mrow = lane & 15;       // A row m / C col n-within-tile
    const int kg   = lane >> 4;       // k-quad
    short8 afr[4];
    #pragma unroll
    for (int kt = 0; kt < 4; ++kt) {  // A[m][kt*32 + kg*8 + j], j=0..7
        const unsigned short* p = panel + mrow * PSTR + kt * 32 + kg * 8;
        union { uint2 u[2]; short8 s; } tmp;
        tmp.u[0] = *(const uint2*)(p);
        tmp.u[1] = *(const uint2*)(p + 4);
        afr[kt] = tmp.s;
    }
    float4v a0 = {0.f, 0.f, 0.f, 0.f};
    float4v a1 = {0.f, 0.f, 0.f, 0.f};
    #pragma unroll
    for (int kt = 0; kt < 4; ++kt) {  // pass 1: W_hi
        a0 = __builtin_amdgcn_mfma_f32_16x16x32_bf16(afr[kt], whi[L][0][kt], a0, 0, 0, 0);
        a1 = __builtin_amdgcn_mfma_f32_16x16x32_bf16(afr[kt], whi[L][1][kt], a1, 0, 0, 0);
    }
    #pragma unroll
    for (int kt = 0; kt < 4; ++kt) {  // pass 2: W_lo
        a0 = __builtin_amdgcn_mfma_f32_16x16x32_bf16(afr[kt], wlo[L][0][kt], a0, 0, 0, 0);
        a1 = __builtin_amdgcn_mfma_f32_16x16x32_bf16(afr[kt], wlo[L][1][kt], a1, 0, 0, 0);
    }
    // C/D layout: col = lane&15, row = (lane>>4)*4 + r   [measured m89/m91]
    const int n0 = (wave * 2 + 0) * 16 + mrow;
    const int n1 = (wave * 2 + 1) * 16 + mrow;
    const int rb = kg * 4;
    #pragma unroll
    for (int r = 0; r < 4; ++r) {
        gb[(rb + r) * GSTR + n0] = a0[r];
        gb[(rb + r) * GSTR + n1] = a1[r];
    }
}

__global__ __launch_bounds__(512, 2) void lstm2_kernel(
    const float* __restrict__ x,
    const float* __restrict__ wih0, const float* __restrict__ whh0,
    const float* __restrict__ bih0, const float* __restrict__ bhh0,
    const float* __restrict__ wih1, const float* __restrict__ whh1,
    const float* __restrict__ bih1, const float* __restrict__ bhh1,
    const float* __restrict__ fcw,  const float* __restrict__ fcb,
    float* __restrict__ out)
{
    // A-panels: rows 0-7 = bf16_hi(inp[b]), rows 8-15 = bf16_lo(inp[b]).
    // panel0 cols [0,64)=x_t, [64,128)=h_l0;  panel1 cols [0,64)=h_l0(t), [64,128)=h_l1.
    __shared__ __align__(16) unsigned short panel0[16 * PSTR];
    __shared__ __align__(16) unsigned short panel1[16 * PSTR];
    __shared__ float gA[16 * GSTR];   // layer-0 raw C (pre-fold)
    __shared__ float gB[16 * GSTR];   // layer-1 raw C
    __shared__ float bias0[256], bias1[256];
    __shared__ float h2buf[NB * 64];
    __shared__ float fcw_s[256];
    __shared__ float fcb_s[4];

    const int tid  = threadIdx.x;
    const int lane = tid & 63;
    const int wave = tid >> 6;              // 8 waves
    const int b0   = blockIdx.x * NB;

    for (int i = tid; i < 256; i += 512) {
        bias0[i] = bih0[i] + bhh0[i];
        bias1[i] = bih1[i] + bhh1[i];
        fcw_s[i] = fcw[i];
    }
    if (tid < 4) fcb_s[tid] = fcb[tid];
    for (int i = tid; i < 16 * PSTR; i += 512) { panel0[i] = 0; panel1[i] = 0; }

    // ---- Load weight B-fragments into registers (resident all 512 steps) ----
    // B layout: n = lane&15 (within n-tile), k = (lane>>4)*8 + j.
    // Combined K=128: k<64 -> w_ih[n][k]; k>=64 -> w_hh[n][k-64]. Wave owns n in [32w,32w+32).
    const int mrow = lane & 15;
    const int kg   = lane >> 4;
    short8 whi[2][2][4], wlo[2][2][4];      // [layer][n-tile][k-tile] = 128 VGPRs
    #pragma unroll
    for (int l = 0; l < 2; ++l) {
        const float* wih = l ? wih1 : wih0;
        const float* whh = l ? whh1 : whh0;
        #pragma unroll
        for (int ni = 0; ni < 2; ++ni) {
            const int n = (wave * 2 + ni) * 16 + mrow;
            #pragma unroll
            for (int kt = 0; kt < 4; ++kt) {
                const int k0 = kt * 32 + kg * 8;
                const float* src = (k0 < 64) ? (wih + n * 64 + k0)
                                             : (whh + n * 64 + (k0 - 64));
                union { short8 s; unsigned short u[8]; } hi8, lo8;
                #pragma unroll
                for (int j = 0; j < 8; ++j) {
                    float w = src[j];
                    unsigned short h = f2bf(w);
                    hi8.u[j] = h;
                    lo8.u[j] = f2bf(w - bf2f(h));
                }
                whi[l][ni][kt] = hi8.s;
                wlo[l][ni][kt] = lo8.s;
            }
        }
    }

    __syncthreads();                        // panels zeroed
    const int bx = tid >> 6;                // x-stage mapping: batch
    const int kx = tid & 63;                // x-stage mapping: feature
    {
        float xv = x[((size_t)(b0 + bx) * T_SEQ + 0) * 64 + kx];
        unsigned short h = f2bf(xv);
        panel0[bx * PSTR + kx]       = h;
        panel0[(bx + 8) * PSTR + kx] = f2bf(xv - bf2f(h));
    }
    float c0 = 0.f, c1 = 0.f;               // cell state: thread owns (b=wave, h=lane)
    __syncthreads();

    const int b  = wave;
    const int hh = lane;

    for (int t = 0; t < T_SEQ; ++t) {
        const int tn = (t + 1 < T_SEQ) ? (t + 1) : (T_SEQ - 1);
        float xv = x[((size_t)(b0 + bx) * T_SEQ + tn) * 64 + kx];  // prefetch x_{t+1}

        // ---- Phase A: layer-0 gates ----
        mfma_phase<0>(panel0, whi, wlo, gA, wave, lane);
        __syncthreads();

        // ---- Phase B: layer-0 elementwise (fold C[b]+C[b+8], LSTM cell) ----
        {
            float gi = gA[b * GSTR + hh]       + gA[(b + 8) * GSTR + hh]       + bias0[hh];
            float gf = gA[b * GSTR + 64 + hh]  + gA[(b + 8) * GSTR + 64 + hh]  + bias0[64 + hh];
            float gg = gA[b * GSTR + 128 + hh] + gA[(b + 8) * GSTR + 128 + hh] + bias0[128 + hh];
            float go = gA[b * GSTR + 192 + hh] + gA[(b + 8) * GSTR + 192 + hh] + bias0[192 + hh];
            float ig = sigm(gi), fg = sigm(gf), gt = tanh_f(gg), og = sigm(go);
            c0 = fg * c0 + ig * gt;
            float hv = og * tanh_f(c0);
            unsigned short hhi = f2bf(hv);
            unsigned short hlo = f2bf(hv - bf2f(hhi));
            panel0[b * PSTR + 64 + hh]       = hhi;   // layer-0 recurrence
            panel0[(b + 8) * PSTR + 64 + hh] = hlo;
            panel1[b * PSTR + hh]            = hhi;   // layer-1 input h1_t
            panel1[(b + 8) * PSTR + hh]      = hlo;
            unsigned short xh = f2bf(xv);              // stage x_{t+1}
            panel0[bx * PSTR + kx]       = xh;
            panel0[(bx + 8) * PSTR + kx] = f2bf(xv - bf2f(xh));
        }
        __syncthreads();

        // ---- Phase C: layer-1 gates ----
        mfma_phase<1>(panel1, whi, wlo, gB, wave, lane);
        __syncthreads();

        // ---- Phase D: layer-1 elementwise (no trailing barrier needed:
        //      next-step hazards are covered by bar-A' and bar-B') ----
        {
            float gi = gB[b * GSTR + hh]       + gB[(b + 8) * GSTR + hh]       + bias1[hh];
            float gf = gB[b * GSTR + 64 + hh]  + gB[(b + 8) * GSTR + 64 + hh]  + bias1[64 + hh];
            float gg = gB[b * GSTR + 128 + hh] + gB[(b + 8) * GSTR + 128 + hh] + bias1[128 + hh];
            float go = gB[b * GSTR + 192 + hh] + gB[(b + 8) * GSTR + 192 + hh] + bias1[192 + hh];
            float ig = sigm(gi), fg = sigm(gf), gt = tanh_f(gg), og = sigm(go);
            c1 = fg * c1 + ig * gt;
            float hv = og * tanh_f(c1);
            unsigned short hhi = f2bf(hv);
            unsigned short hlo = f2bf(hv - bf2f(hhi));
            panel1[b * PSTR + 64 + hh]       = hhi;   // layer-1 recurrence
            panel1[(b + 8) * PSTR + 64 + hh] = hlo;
            if (t == T_SEQ - 1) h2buf[b * 64 + hh] = hv;
        }
    }

    __syncthreads();
    // ---- FC head: out[b][nc] = h2_last[b] . fc_w[nc] + fc_b[nc] ----
    if (tid < 32) {
        const int bb = tid >> 2;
        const int nc = tid & 3;
        float s = fcb_s[nc];
        #pragma unroll 8
        for (int h = 0; h < 64; ++h) s += h2buf[bb * 64 + h] * fcw_s[nc * 64 + h];
        out[(size_t)(b0 + bb) * 4 + nc] = s;
    }
}

extern "C" void kernel_launch(void* const* d_in, const int* in_sizes, int n_in,
                              void* d_out, int out_size, void* d_ws, size_t ws_size,
                              hipStream_t stream) {
    const float* x    = (const float*)d_in[0];
    const float* wih0 = (const float*)d_in[1];
    const float* whh0 = (const float*)d_in[2];
    const float* bih0 = (const float*)d_in[3];
    const float* bhh0 = (const float*)d_in[4];
    const float* wih1 = (const float*)d_in[5];
    const float* whh1 = (const float*)d_in[6];
    const float* bih1 = (const float*)d_in[7];
    const float* bhh1 = (const float*)d_in[8];
    const float* fcw  = (const float*)d_in[9];
    const float* fcb  = (const float*)d_in[10];
    float* out = (float*)d_out;
    (void)d_ws; (void)ws_size; (void)in_sizes; (void)n_in; (void)out_size;

    lstm2_kernel<<<dim3(2048 / NB), dim3(512), 0, stream>>>(
        x, wih0, whh0, bih0, bhh0, wih1, whh1, bih1, bhh1, fcw, fcb, out);
}